// Round 14
// baseline (70.687 us; speedup 1.0000x reference)
//
#include <hip/hip_runtime.h>

#define B_    4
#define N1_   16384
#define N2_   4096
#define C1_   64
#define C2_   128
#define BQ    64            // queries per block
#define WV_   8             // waves per block

typedef __attribute__((ext_vector_type(8))) short bf16x8;
typedef __attribute__((ext_vector_type(4))) float f32x4;
typedef __attribute__((ext_vector_type(16))) float f32x16;
typedef __attribute__((ext_vector_type(4))) unsigned short u16x4;

__device__ __forceinline__ unsigned short f2bf(float f) {
  unsigned int u = __builtin_bit_cast(unsigned int, f);
  unsigned int r = (u + 0x7FFFu + ((u >> 16) & 1u)) >> 16;
  return (unsigned short)r;
}
__device__ __forceinline__ float bf2f(unsigned short h) {
  return __builtin_bit_cast(float, (unsigned)h << 16);
}
__device__ __forceinline__ float fmin3(float a, float b, float c) {
  return fminf(fminf(a, b), c);   // clang fuses to v_min3_f32
}
__device__ __forceinline__ float min16(const f32x16 v) {
  float m = fmin3(v[0], v[1], v[2]);
  m = fmin3(m, v[3], v[4]);  m = fmin3(m, v[5], v[6]);
  m = fmin3(m, v[7], v[8]);  m = fmin3(m, v[9], v[10]);
  m = fmin3(m, v[11], v[12]); m = fmin3(m, v[13], v[14]);
  return fminf(m, v[15]);
}

// exact insert of 64-bit lexicographic key (d_bits<<32 | idx) via f64 min/max (R3-proven)
#define INS3D(x, m0, m1, m2) do {           \
    double _a = fmax((x), (m0));            \
    (m0) = fmin((x), (m0));                 \
    double _b = fmax(_a, (m1));             \
    (m1) = fmin(_a, (m1));                  \
    (m2) = fmin(_b, (m2));                  \
  } while (0)

// f32 value-only insert (keep 3 smallest)
#define INS3F(x, m0, m1, m2) do {           \
    float _a = fmaxf((x), (m0));            \
    (m0) = fminf((x), (m0));                \
    float _b = fmaxf(_a, (m1));             \
    (m1) = fminf(_a, (m1));                 \
    (m2) = fminf(_b, (m2));                 \
  } while (0)

#define KINF __builtin_bit_cast(double, 0x7FF0000000000000ULL)

// ---- prep: f32 cand (-2x,-2y,-2z,|c|^2), bf16-split candA (16 u16/cand), W transposes ----
__global__ void prep_kernel(const float* __restrict__ xyz2, const float* __restrict__ W1,
                            const float* __restrict__ W2,
                            float4* __restrict__ cand, unsigned short* __restrict__ candA,
                            unsigned short* __restrict__ w1t, unsigned short* __restrict__ w2t) {
  int t = blockIdx.x * 256 + threadIdx.x;
  const int NC  = B_ * N2_;     // 16384
  const int NW1 = 192 * 128;    // 24576
  const int NW2 = 128 * 128;    // 16384
  if (t < NC) {
    float x = xyz2[t * 3 + 0], y = xyz2[t * 3 + 1], z = xyz2[t * 3 + 2];
    float c2x = -2.f * x, c2y = -2.f * y, c2z = -2.f * z;
    float w = x * x + y * y + z * z;
    cand[t] = make_float4(c2x, c2y, c2z, w);
    unsigned short hx = f2bf(c2x), hy = f2bf(c2y), hz = f2bf(c2z), wh = f2bf(w);
    unsigned short lx = f2bf(c2x - bf2f(hx)), ly = f2bf(c2y - bf2f(hy));
    unsigned short lz = f2bf(c2z - bf2f(hz)), wl = f2bf(w - bf2f(wh));
    u16x4* pa = (u16x4*)(candA + (size_t)t * 16);
    pa[0] = (u16x4){hx, hy, hz, wh};
    pa[1] = (u16x4){hx, hy, hz, wl};
    pa[2] = (u16x4){lx, ly, lz, 0};
    pa[3] = (u16x4){0, 0, 0, 0};
  } else if (t < NC + NW1) {
    int i = t - NC; int k = i >> 7, c = i & 127;
    w1t[c * 192 + k] = f2bf(W1[i]);
  } else if (t < NC + NW1 + NW2) {
    int i = t - NC - NW1; int k = i >> 7, c = i & 127;
    w2t[c * 128 + k] = f2bf(W2[i]);
  }
}

// ---- fused: 32x32x16-MFMA-filtered exact three_nn + interp + concat + MLP ----
__global__ __launch_bounds__(512, 8) void fused_kernel(
    const float* __restrict__ xyz1, const float* __restrict__ points1,
    const float* __restrict__ points2, const float4* __restrict__ cand,
    const unsigned short* __restrict__ candA,
    const unsigned short* __restrict__ w1t, const unsigned short* __restrict__ w2t,
    const float* __restrict__ bb1, const float* __restrict__ bb2,
    float* __restrict__ out) {

  // 25600-byte union; scan-phase overlays then Ash/Hsh for the MLP
  __shared__ __align__(16) unsigned char Ubuf[BQ * 200 * 2];
  unsigned short* QbufL = (unsigned short*)Ubuf;           // [64][16] u16   = 2048
  float*    LminL = (float*)(Ubuf + 2048);                 // [64][20] f32   = 5120 -> 7168
  float*    thrL  = (float*)(Ubuf + 7168);                 // [64]           -> 7424
  unsigned* cntL  = (unsigned*)(Ubuf + 7424);              // [64]           -> 7680
  float4*   sQf   = (float4*)(Ubuf + 7680);                // [64]           -> 8704
  uint2*    buckL = (uint2*)(Ubuf + 8704);                 // [64][33] uint2 = 16896 -> 25600
  unsigned short (*Ash)[200] = (unsigned short (*)[200])Ubuf;
  unsigned short (*Hsh)[136] = (unsigned short (*)[136])Ubuf;
  __shared__ float sW[BQ][3];
  __shared__ int   sJ[BQ][3];

  const int tid  = threadIdx.x;
  const int lane = tid & 63;
  const int wv   = __builtin_amdgcn_readfirstlane(tid >> 6);
  const int bid  = blockIdx.x;
  const int bb   = bid >> 8;            // 256 blocks per batch
  const int n0   = (bid & 255) * BQ;

  // ---------- phase 0: query params + bf16-split Q fragments ----------
  if (tid < BQ) {
    const float* xp = xyz1 + ((size_t)bb * N1_ + n0 + tid) * 3;
    float x = xp[0], y = xp[1], z = xp[2];
    float q1 = fmaf(x, x, fmaf(y, y, z * z));
    sQf[tid] = make_float4(x, y, z, q1);
    unsigned short hx = f2bf(x), hy = f2bf(y), hz = f2bf(z);
    unsigned short lx = f2bf(x - bf2f(hx)), ly = f2bf(y - bf2f(hy)), lz = f2bf(z - bf2f(hz));
    const unsigned short one = 0x3F80;
    u16x4* qr = (u16x4*)(QbufL + tid * 16);
    qr[0] = (u16x4){hx, hy, hz, one};
    qr[1] = (u16x4){lx, ly, lz, one};
    qr[2] = (u16x4){hx, hy, hz, 0};
    qr[3] = (u16x4){0, 0, 0, 0};
    cntL[tid] = 0u;
  }
  __syncthreads();

  const int arow  = lane & 31;          // A-row (cand) / B-col (query) within 32-tile
  const int ahalf = lane >> 5;          // k-half (0..1), 8 bf16 each
  const f32x16 zacc = (f32x16){0.f,0.f,0.f,0.f,0.f,0.f,0.f,0.f,
                               0.f,0.f,0.f,0.f,0.f,0.f,0.f,0.f};

  // B fragments: 2 query-tiles of 32; all 64 lanes carry data
  bf16x8 bfq[2];
  #pragma unroll
  for (int nt = 0; nt < 2; ++nt)
    bfq[nt] = *(const bf16x8*)(QbufL + (nt * 32 + arow) * 16 + ahalf * 8);

  const unsigned short* cAb = candA + (size_t)bb * N2_ * 16;
  const int tbase = wv * 16;            // 16 cand-tiles (512 cands) per wave

  #define LOADT(tt) (*(const bf16x8*)(cAb + ((size_t)((tt) * 32 + arow)) * 16 + ahalf * 8))

  // ---------- pass 1 (MFMA): per-lane min over its (256-cand, query) subset ----------
  {
    float vmin[2] = {1e30f, 1e30f};
    bf16x8 afA = LOADT(tbase);
    bf16x8 afB = LOADT(tbase + 1);
    for (int t = 0; t < 16; ++t) {
      const int tn = (t + 2 < 16) ? (tbase + t + 2) : (tbase + t);
      const bf16x8 afC = LOADT(tn);
      #pragma unroll
      for (int nt = 0; nt < 2; ++nt) {
        const f32x16 acc = __builtin_amdgcn_mfma_f32_32x32x16_bf16(afA, bfq[nt], zacc, 0, 0, 0);
        vmin[nt] = fminf(vmin[nt], min16(acc));
      }
      afA = afB; afB = afC;
    }
    #pragma unroll
    for (int nt = 0; nt < 2; ++nt)
      LminL[(nt * 32 + arow) * 20 + wv * 2 + ahalf] = vmin[nt];
  }
  __syncthreads();

  // ---------- threshold: 3rd-smallest of 16 subset-mins (>= v3) + rigorous margin ----------
  if (tid < BQ) {
    const float* Lr = LminL + tid * 20;
    float m0 = 1e30f, m1 = 1e30f, m2 = 1e30f;
    #pragma unroll
    for (int i = 0; i < 16; ++i) {
      const float v = Lr[i];
      INS3F(v, m0, m1, m2);
    }
    thrL[tid] = m2 + 6e-3f + 0.03125f * fabsf(m2);
  }
  __syncthreads();

  // ---------- pass 2 (MFMA): guarded capture of cand idx with s <= thr ----------
  {
    float thrv[2];
    #pragma unroll
    for (int nt = 0; nt < 2; ++nt) thrv[nt] = thrL[nt * 32 + arow];

    bf16x8 afA = LOADT(tbase);
    bf16x8 afB = LOADT(tbase + 1);
    for (int t = 0; t < 16; ++t) {
      const int tn = (t + 2 < 16) ? (tbase + t + 2) : (tbase + t);
      const bf16x8 afC = LOADT(tn);
      const int tile = tbase + t;
      #pragma unroll
      for (int nt = 0; nt < 2; ++nt) {
        const f32x16 acc = __builtin_amdgcn_mfma_f32_32x32x16_bf16(afA, bfq[nt], zacc, 0, 0, 0);
        const float am = min16(acc);            // cheap common path (9 ops)
        if (am <= thrv[nt]) {                   // rare per-lane; exec-masked body
          unsigned msk = 0u;
          #pragma unroll
          for (int reg = 0; reg < 16; ++reg)
            msk |= (acc[reg] <= thrv[nt]) ? (1u << reg) : 0u;
          const int q = nt * 32 + arow;
          do {
            const int reg = __builtin_ctz(msk);
            msk &= msk - 1u;
            // C/D layout (m74/m101): row = (reg&3) + 8*(reg>>2) + 4*(lane>>5)
            const unsigned idx =
                (unsigned)(tile * 32 + (reg & 3) + 8 * (reg >> 2) + 4 * ahalf);
            const unsigned slot = atomicAdd(&cntL[q], 1u);
            if (slot < 32u) buckL[q * 33 + slot].y = idx;   // idx only; d filled next phase
          } while (msk);
        }
      }
      afA = afB; afB = afC;
    }
  }
  __syncthreads();

  // ---------- phase 2.5: parallel exact-d fill (one scattered L2 load per thread) ----------
  {
    const int q  = tid >> 3;            // 8 threads per query
    const int s0 = tid & 7;
    const int cn = (int)min(cntL[q], 32u);
    const float4 qv = sQf[q];
    const float4* cb = cand + (size_t)bb * N2_;
    for (int slot = s0; slot < cn; slot += 8) {
      const unsigned idx = buckL[q * 33 + slot].y;
      const float4 cp = cb[idx];
      // bit-identical exact chain (R7-proven)
      const float d = fmaf(cp.x, qv.x, fmaf(cp.y, qv.y, fmaf(cp.z, qv.z, qv.w + cp.w)));
      buckL[q * 33 + slot].x = __builtin_bit_cast(unsigned, d);
    }
  }
  __syncthreads();

  // ---------- exact merge (pure LDS): f64 lexicographic top-3, weights ----------
  if (tid < BQ) {
    const int q = tid;
    const int cn = (int)min(cntL[q], 32u);
    double k0 = KINF, k1 = KINF, k2 = KINF;
    for (int i = 0; i < cn; ++i) {
      const uint2 e = buckL[q * 33 + i];
      const unsigned long long kk = ((unsigned long long)e.x << 32) | e.y;
      const double xk = __builtin_bit_cast(double, kk);
      INS3D(xk, k0, k1, k2);
    }
    const unsigned long long u0 = __builtin_bit_cast(unsigned long long, k0);
    const unsigned long long u1 = __builtin_bit_cast(unsigned long long, k1);
    const unsigned long long u2 = __builtin_bit_cast(unsigned long long, k2);
    const float d0 = fmaxf(__builtin_bit_cast(float, (unsigned)(u0 >> 32)), 1e-10f);
    const float d1 = fmaxf(__builtin_bit_cast(float, (unsigned)(u1 >> 32)), 1e-10f);
    const float d2 = fmaxf(__builtin_bit_cast(float, (unsigned)(u2 >> 32)), 1e-10f);
    const float r0 = 1.f / d0, r1 = 1.f / d1, r2 = 1.f / d2;
    const float inorm = 1.f / (r0 + r1 + r2);
    sW[q][0] = r0 * inorm; sW[q][1] = r1 * inorm; sW[q][2] = r2 * inorm;
    sJ[q][0] = (int)(unsigned)u0; sJ[q][1] = (int)(unsigned)u1; sJ[q][2] = (int)(unsigned)u2;
  }
  __syncthreads();

  // ---------- phase 3: gather + interpolate + concat into bf16 A tile ----------
  {
    const int qq = tid >> 3, cq = tid & 7;    // 8 threads per query
    const float w0 = sW[qq][0], w1 = sW[qq][1], w2 = sW[qq][2];
    const float* f0 = points2 + ((size_t)bb * N2_ + sJ[qq][0]) * C2_;
    const float* f1 = points2 + ((size_t)bb * N2_ + sJ[qq][1]) * C2_;
    const float* f2 = points2 + ((size_t)bb * N2_ + sJ[qq][2]) * C2_;
    #pragma unroll
    for (int c = cq * 16; c < cq * 16 + 16; c += 4) {
      const float4 a  = *(const float4*)(f0 + c);
      const float4 bv = *(const float4*)(f1 + c);
      const float4 cv = *(const float4*)(f2 + c);
      u16x4 pk;
      pk.x = f2bf(fmaf(w2, cv.x, fmaf(w1, bv.x, w0 * a.x)));
      pk.y = f2bf(fmaf(w2, cv.y, fmaf(w1, bv.y, w0 * a.y)));
      pk.z = f2bf(fmaf(w2, cv.z, fmaf(w1, bv.z, w0 * a.z)));
      pk.w = f2bf(fmaf(w2, cv.w, fmaf(w1, bv.w, w0 * a.w)));
      *(u16x4*)&Ash[qq][c] = pk;
    }
    const float* p1 = points1 + ((size_t)bb * N1_ + n0 + qq) * C1_;
    #pragma unroll
    for (int c = cq * 8; c < cq * 8 + 8; c += 4) {
      const float4 v = *(const float4*)(p1 + c);
      u16x4 pk;
      pk.x = f2bf(v.x); pk.y = f2bf(v.y); pk.z = f2bf(v.z); pk.w = f2bf(v.w);
      *(u16x4*)&Ash[qq][128 + c] = pk;
    }
  }
  __syncthreads();

  // ---------- phase 4: GEMM1  (64x192) x (192x128), wave = 16-col slice ----------
  const int lr = lane & 15;
  const int lg = lane >> 4;
  const int col = wv * 16 + lr;
  f32x4 acc1[4];
  #pragma unroll
  for (int m = 0; m < 4; ++m) acc1[m] = (f32x4){0.f, 0.f, 0.f, 0.f};

  #pragma unroll
  for (int kk = 0; kk < 6; ++kk) {
    const int kof = kk * 32 + lg * 8;
    const bf16x8 bfr = *(const bf16x8*)(w1t + (size_t)col * 192 + kof);
    #pragma unroll
    for (int m = 0; m < 4; ++m) {
      const bf16x8 af = *(const bf16x8*)&Ash[m * 16 + lr][kof];
      acc1[m] = __builtin_amdgcn_mfma_f32_16x16x32_bf16(af, bfr, acc1[m], 0, 0, 0);
    }
  }
  __syncthreads();   // all waves done READING Ash before H overwrites the union

  {
    const float bias = bb1[col];
    #pragma unroll
    for (int m = 0; m < 4; ++m)
      #pragma unroll
      for (int e = 0; e < 4; ++e) {
        const int row = m * 16 + lg * 4 + e;
        Hsh[row][col] = f2bf(fmaxf(acc1[m][e] + bias, 0.f));
      }
  }
  __syncthreads();

  // ---------- phase 5: GEMM2  (64x128) x (128x128), relu, store f32 ----------
  f32x4 acc2[4];
  #pragma unroll
  for (int m = 0; m < 4; ++m) acc2[m] = (f32x4){0.f, 0.f, 0.f, 0.f};

  #pragma unroll
  for (int kk = 0; kk < 4; ++kk) {
    const int kof = kk * 32 + lg * 8;
    const bf16x8 bfr = *(const bf16x8*)(w2t + (size_t)col * 128 + kof);
    #pragma unroll
    for (int m = 0; m < 4; ++m) {
      const bf16x8 af = *(const bf16x8*)&Hsh[m * 16 + lr][kof];
      acc2[m] = __builtin_amdgcn_mfma_f32_16x16x32_bf16(af, bfr, acc2[m], 0, 0, 0);
    }
  }
  {
    const float bias = bb2[col];
    #pragma unroll
    for (int m = 0; m < 4; ++m)
      #pragma unroll
      for (int e = 0; e < 4; ++e) {
        const int row = m * 16 + lg * 4 + e;
        out[((size_t)bb * N1_ + n0 + row) * 128 + col] = fmaxf(acc2[m][e] + bias, 0.f);
      }
  }
}

extern "C" void kernel_launch(void* const* d_in, const int* in_sizes, int n_in,
                              void* d_out, int out_size, void* d_ws, size_t ws_size,
                              hipStream_t stream) {
  const float* xyz1    = (const float*)d_in[0];
  const float* xyz2    = (const float*)d_in[1];
  const float* points1 = (const float*)d_in[2];
  const float* points2 = (const float*)d_in[3];
  const float* W1      = (const float*)d_in[4];
  const float* b1      = (const float*)d_in[5];
  const float* W2      = (const float*)d_in[6];
  const float* b2      = (const float*)d_in[7];
  float* out = (float*)d_out;

  char* ws = (char*)d_ws;
  float4*         cand  = (float4*)ws;                        // 16384*16  = 262144 B
  unsigned short* candA = (unsigned short*)(ws + 262144);     // 16384*32  = 524288 B
  unsigned short* w1t   = (unsigned short*)(ws + 786432);     // 192*128*2 =  49152 B
  unsigned short* w2t   = (unsigned short*)(ws + 835584);     // 128*128*2 =  32768 B

  prep_kernel<<<224, 256, 0, stream>>>(xyz2, W1, W2, cand, candA, w1t, w2t);
  fused_kernel<<<1024, 512, 0, stream>>>(xyz1, points1, points2, cand, candA,
                                         w1t, w2t, b1, b2, out);
}

// Round 15
// 67.592 us; speedup vs baseline: 1.0458x; 1.0458x over previous
//
#include <hip/hip_runtime.h>

#define B_    4
#define N1_   16384
#define N2_   4096
#define C1_   64
#define C2_   128
#define BQ    64            // queries per block
#define WV_   8             // waves per block

typedef __attribute__((ext_vector_type(8))) short bf16x8;
typedef __attribute__((ext_vector_type(4))) float f32x4;
typedef __attribute__((ext_vector_type(16))) float f32x16;
typedef __attribute__((ext_vector_type(4))) unsigned short u16x4;

__device__ __forceinline__ unsigned short f2bf(float f) {
  unsigned int u = __builtin_bit_cast(unsigned int, f);
  unsigned int r = (u + 0x7FFFu + ((u >> 16) & 1u)) >> 16;
  return (unsigned short)r;
}
__device__ __forceinline__ float bf2f(unsigned short h) {
  return __builtin_bit_cast(float, (unsigned)h << 16);
}
__device__ __forceinline__ float fmin3(float a, float b, float c) {
  return fminf(fminf(a, b), c);   // clang fuses to v_min3_f32
}
__device__ __forceinline__ float min16(const f32x16 v) {
  float m = fmin3(v[0], v[1], v[2]);
  m = fmin3(m, v[3], v[4]);  m = fmin3(m, v[5], v[6]);
  m = fmin3(m, v[7], v[8]);  m = fmin3(m, v[9], v[10]);
  m = fmin3(m, v[11], v[12]); m = fmin3(m, v[13], v[14]);
  return fminf(m, v[15]);
}

// exact insert of 64-bit lexicographic key (d_bits<<32 | idx) via f64 min/max (R3-proven)
#define INS3D(x, m0, m1, m2) do {           \
    double _a = fmax((x), (m0));            \
    (m0) = fmin((x), (m0));                 \
    double _b = fmax(_a, (m1));             \
    (m1) = fmin(_a, (m1));                  \
    (m2) = fmin(_b, (m2));                  \
  } while (0)

// f32 value-only insert (keep 3 smallest)
#define INS3F(x, m0, m1, m2) do {           \
    float _a = fmaxf((x), (m0));            \
    (m0) = fminf((x), (m0));                \
    float _b = fmaxf(_a, (m1));             \
    (m1) = fminf(_a, (m1));                 \
    (m2) = fminf(_b, (m2));                 \
  } while (0)

#define KINF __builtin_bit_cast(double, 0x7FF0000000000000ULL)

// ---- prep: f32 cand (-2x,-2y,-2z,|c|^2), bf16-split candA (16 u16/cand), W transposes ----
__global__ void prep_kernel(const float* __restrict__ xyz2, const float* __restrict__ W1,
                            const float* __restrict__ W2,
                            float4* __restrict__ cand, unsigned short* __restrict__ candA,
                            unsigned short* __restrict__ w1t, unsigned short* __restrict__ w2t) {
  int t = blockIdx.x * 256 + threadIdx.x;
  const int NC  = B_ * N2_;     // 16384
  const int NW1 = 192 * 128;    // 24576
  const int NW2 = 128 * 128;    // 16384
  if (t < NC) {
    float x = xyz2[t * 3 + 0], y = xyz2[t * 3 + 1], z = xyz2[t * 3 + 2];
    float c2x = -2.f * x, c2y = -2.f * y, c2z = -2.f * z;
    float w = x * x + y * y + z * z;
    cand[t] = make_float4(c2x, c2y, c2z, w);
    unsigned short hx = f2bf(c2x), hy = f2bf(c2y), hz = f2bf(c2z), wh = f2bf(w);
    unsigned short lx = f2bf(c2x - bf2f(hx)), ly = f2bf(c2y - bf2f(hy));
    unsigned short lz = f2bf(c2z - bf2f(hz)), wl = f2bf(w - bf2f(wh));
    u16x4* pa = (u16x4*)(candA + (size_t)t * 16);
    pa[0] = (u16x4){hx, hy, hz, wh};
    pa[1] = (u16x4){hx, hy, hz, wl};
    pa[2] = (u16x4){lx, ly, lz, 0};
    pa[3] = (u16x4){0, 0, 0, 0};
  } else if (t < NC + NW1) {
    int i = t - NC; int k = i >> 7, c = i & 127;
    w1t[c * 192 + k] = f2bf(W1[i]);
  } else if (t < NC + NW1 + NW2) {
    int i = t - NC - NW1; int k = i >> 7, c = i & 127;
    w2t[c * 128 + k] = f2bf(W2[i]);
  }
}

// ---- fused: 32x32x16-MFMA-filtered exact three_nn + interp + concat + MLP ----
__global__ __launch_bounds__(512, 8) void fused_kernel(
    const float* __restrict__ xyz1, const float* __restrict__ points1,
    const float* __restrict__ points2, const float4* __restrict__ cand,
    const unsigned short* __restrict__ candA,
    const unsigned short* __restrict__ w1t, const unsigned short* __restrict__ w2t,
    const float* __restrict__ bb1, const float* __restrict__ bb2,
    float* __restrict__ out) {

  // 25600-byte union; scan-phase overlays then Ash/Hsh for the MLP
  __shared__ __align__(16) unsigned char Ubuf[BQ * 200 * 2];
  unsigned short* QbufL = (unsigned short*)Ubuf;           // [64][16] u16   = 2048
  float*    LminL = (float*)(Ubuf + 2048);                 // [64][20] f32   = 5120 -> 7168
  float*    thrL  = (float*)(Ubuf + 7168);                 // [64]           -> 7424
  unsigned* buckL = (unsigned*)(Ubuf + 7424);              // [64][33]       = 8448 -> 15872
  unsigned* cntL  = (unsigned*)(Ubuf + 15872);             // [64]           -> 16128
  float4*   sQf   = (float4*)(Ubuf + 16128);               // [64]           -> 17152
  unsigned short (*Ash)[200] = (unsigned short (*)[200])Ubuf;
  unsigned short (*Hsh)[136] = (unsigned short (*)[136])Ubuf;
  __shared__ float sW[BQ][3];
  __shared__ int   sJ[BQ][3];

  const int tid  = threadIdx.x;
  const int lane = tid & 63;
  const int wv   = __builtin_amdgcn_readfirstlane(tid >> 6);
  const int bid  = blockIdx.x;
  const int bb   = bid >> 8;            // 256 blocks per batch
  const int n0   = (bid & 255) * BQ;

  // ---------- phase 0: query params + bf16-split Q fragments ----------
  if (tid < BQ) {
    const float* xp = xyz1 + ((size_t)bb * N1_ + n0 + tid) * 3;
    float x = xp[0], y = xp[1], z = xp[2];
    float q1 = fmaf(x, x, fmaf(y, y, z * z));
    sQf[tid] = make_float4(x, y, z, q1);
    unsigned short hx = f2bf(x), hy = f2bf(y), hz = f2bf(z);
    unsigned short lx = f2bf(x - bf2f(hx)), ly = f2bf(y - bf2f(hy)), lz = f2bf(z - bf2f(hz));
    const unsigned short one = 0x3F80;
    u16x4* qr = (u16x4*)(QbufL + tid * 16);
    qr[0] = (u16x4){hx, hy, hz, one};
    qr[1] = (u16x4){lx, ly, lz, one};
    qr[2] = (u16x4){hx, hy, hz, 0};
    qr[3] = (u16x4){0, 0, 0, 0};
    cntL[tid] = 0u;
  }
  __syncthreads();

  const int arow  = lane & 31;          // A-row (cand) / B-col (query) within 32-tile
  const int ahalf = lane >> 5;          // k-half (0..1), 8 bf16 each
  const f32x16 zacc = (f32x16){0.f,0.f,0.f,0.f,0.f,0.f,0.f,0.f,
                               0.f,0.f,0.f,0.f,0.f,0.f,0.f,0.f};

  // B fragments: 2 query-tiles of 32; all 64 lanes carry data
  bf16x8 bfq[2];
  #pragma unroll
  for (int nt = 0; nt < 2; ++nt)
    bfq[nt] = *(const bf16x8*)(QbufL + (nt * 32 + arow) * 16 + ahalf * 8);

  const unsigned short* cAb = candA + (size_t)bb * N2_ * 16;
  const int tbase = wv * 16;            // 16 cand-tiles (512 cands) per wave

  // ---------- pass 1 (MFMA): per-lane min over its (256-cand, query) subset ----------
  {
    float vmin[2] = {1e30f, 1e30f};
    bf16x8 af = *(const bf16x8*)(cAb + ((size_t)(tbase * 32 + arow)) * 16 + ahalf * 8);
    for (int t = 0; t < 16; ++t) {
      bf16x8 afn = af;
      if (t < 15)
        afn = *(const bf16x8*)(cAb + ((size_t)((tbase + t + 1) * 32 + arow)) * 16 + ahalf * 8);
      #pragma unroll
      for (int nt = 0; nt < 2; ++nt) {
        const f32x16 acc = __builtin_amdgcn_mfma_f32_32x32x16_bf16(af, bfq[nt], zacc, 0, 0, 0);
        vmin[nt] = fminf(vmin[nt], min16(acc));
      }
      af = afn;
    }
    #pragma unroll
    for (int nt = 0; nt < 2; ++nt)
      LminL[(nt * 32 + arow) * 20 + wv * 2 + ahalf] = vmin[nt];
  }
  __syncthreads();

  // ---------- threshold: 3rd-smallest of 16 subset-mins (>= v3) + rigorous margin ----------
  if (tid < BQ) {
    const float* Lr = LminL + tid * 20;
    float m0 = 1e30f, m1 = 1e30f, m2 = 1e30f;
    #pragma unroll
    for (int i = 0; i < 16; ++i) {
      const float v = Lr[i];
      INS3F(v, m0, m1, m2);
    }
    thrL[tid] = m2 + 6e-3f + 0.03125f * fabsf(m2);
  }
  __syncthreads();

  // ---------- pass 2 (MFMA): capture cand idx with s <= thr into per-query buckets ----------
  {
    float thrv[2];
    #pragma unroll
    for (int nt = 0; nt < 2; ++nt) thrv[nt] = thrL[nt * 32 + arow];

    bf16x8 af = *(const bf16x8*)(cAb + ((size_t)(tbase * 32 + arow)) * 16 + ahalf * 8);
    for (int t = 0; t < 16; ++t) {
      bf16x8 afn = af;
      if (t < 15)
        afn = *(const bf16x8*)(cAb + ((size_t)((tbase + t + 1) * 32 + arow)) * 16 + ahalf * 8);
      const int tile = tbase + t;
      #pragma unroll
      for (int nt = 0; nt < 2; ++nt) {
        const f32x16 acc = __builtin_amdgcn_mfma_f32_32x32x16_bf16(af, bfq[nt], zacc, 0, 0, 0);
        const float am = min16(acc);
        if (am <= thrv[nt]) {
          const int q = nt * 32 + arow;
          #pragma unroll
          for (int reg = 0; reg < 16; ++reg) {
            if (acc[reg] <= thrv[nt]) {
              // C/D layout (m74/m101): row = (reg&3) + 8*(reg>>2) + 4*(lane>>5)
              const unsigned idx =
                  (unsigned)(tile * 32 + (reg & 3) + 8 * (reg >> 2) + 4 * ahalf);
              const unsigned slot = atomicAdd(&cntL[q], 1u);
              if (slot < 32u) buckL[q * 33 + slot] = idx;
            }
          }
        }
      }
      af = afn;
    }
  }
  __syncthreads();

  // ---------- exact merge: recompute d (bit-identical chain), f64 lex top-3, weights ----------
  if (tid < BQ) {
    const int q = tid;
    const int cn = (int)min(cntL[q], 32u);
    const float4 qv = sQf[q];
    const float4* cb = cand + (size_t)bb * N2_;
    double k0 = KINF, k1 = KINF, k2 = KINF;
    for (int i = 0; i < cn; ++i) {
      const unsigned idx = buckL[q * 33 + i];
      const float4 cp = cb[idx];
      const float d = fmaf(cp.x, qv.x, fmaf(cp.y, qv.y, fmaf(cp.z, qv.z, qv.w + cp.w)));
      const unsigned long long kk =
          ((unsigned long long)__builtin_bit_cast(unsigned, d) << 32) | idx;
      const double xk = __builtin_bit_cast(double, kk);
      INS3D(xk, k0, k1, k2);
    }
    const unsigned long long u0 = __builtin_bit_cast(unsigned long long, k0);
    const unsigned long long u1 = __builtin_bit_cast(unsigned long long, k1);
    const unsigned long long u2 = __builtin_bit_cast(unsigned long long, k2);
    const float d0 = fmaxf(__builtin_bit_cast(float, (unsigned)(u0 >> 32)), 1e-10f);
    const float d1 = fmaxf(__builtin_bit_cast(float, (unsigned)(u1 >> 32)), 1e-10f);
    const float d2 = fmaxf(__builtin_bit_cast(float, (unsigned)(u2 >> 32)), 1e-10f);
    const float r0 = 1.f / d0, r1 = 1.f / d1, r2 = 1.f / d2;
    const float inorm = 1.f / (r0 + r1 + r2);
    sW[q][0] = r0 * inorm; sW[q][1] = r1 * inorm; sW[q][2] = r2 * inorm;
    sJ[q][0] = (int)(unsigned)u0; sJ[q][1] = (int)(unsigned)u1; sJ[q][2] = (int)(unsigned)u2;
  }
  __syncthreads();

  // ---------- phase 3: gather + interpolate + concat into bf16 A tile ----------
  {
    const int qq = tid >> 3, cq = tid & 7;    // 8 threads per query
    const float w0 = sW[qq][0], w1 = sW[qq][1], w2 = sW[qq][2];
    const float* f0 = points2 + ((size_t)bb * N2_ + sJ[qq][0]) * C2_;
    const float* f1 = points2 + ((size_t)bb * N2_ + sJ[qq][1]) * C2_;
    const float* f2 = points2 + ((size_t)bb * N2_ + sJ[qq][2]) * C2_;
    #pragma unroll
    for (int c = cq * 16; c < cq * 16 + 16; c += 4) {
      const float4 a  = *(const float4*)(f0 + c);
      const float4 bv = *(const float4*)(f1 + c);
      const float4 cv = *(const float4*)(f2 + c);
      u16x4 pk;
      pk.x = f2bf(fmaf(w2, cv.x, fmaf(w1, bv.x, w0 * a.x)));
      pk.y = f2bf(fmaf(w2, cv.y, fmaf(w1, bv.y, w0 * a.y)));
      pk.z = f2bf(fmaf(w2, cv.z, fmaf(w1, bv.z, w0 * a.z)));
      pk.w = f2bf(fmaf(w2, cv.w, fmaf(w1, bv.w, w0 * a.w)));
      *(u16x4*)&Ash[qq][c] = pk;
    }
    const float* p1 = points1 + ((size_t)bb * N1_ + n0 + qq) * C1_;
    #pragma unroll
    for (int c = cq * 8; c < cq * 8 + 8; c += 4) {
      const float4 v = *(const float4*)(p1 + c);
      u16x4 pk;
      pk.x = f2bf(v.x); pk.y = f2bf(v.y); pk.z = f2bf(v.z); pk.w = f2bf(v.w);
      *(u16x4*)&Ash[qq][128 + c] = pk;
    }
  }
  __syncthreads();

  // ---------- phase 4: GEMM1  (64x192) x (192x128), wave = 16-col slice ----------
  const int lr = lane & 15;
  const int lg = lane >> 4;
  const int col = wv * 16 + lr;
  f32x4 acc1[4];
  #pragma unroll
  for (int m = 0; m < 4; ++m) acc1[m] = (f32x4){0.f, 0.f, 0.f, 0.f};

  #pragma unroll
  for (int kk = 0; kk < 6; ++kk) {
    const int kof = kk * 32 + lg * 8;
    const bf16x8 bfr = *(const bf16x8*)(w1t + (size_t)col * 192 + kof);
    #pragma unroll
    for (int m = 0; m < 4; ++m) {
      const bf16x8 af = *(const bf16x8*)&Ash[m * 16 + lr][kof];
      acc1[m] = __builtin_amdgcn_mfma_f32_16x16x32_bf16(af, bfr, acc1[m], 0, 0, 0);
    }
  }
  __syncthreads();   // all waves done READING Ash before H overwrites the union

  {
    const float bias = bb1[col];
    #pragma unroll
    for (int m = 0; m < 4; ++m)
      #pragma unroll
      for (int e = 0; e < 4; ++e) {
        const int row = m * 16 + lg * 4 + e;
        Hsh[row][col] = f2bf(fmaxf(acc1[m][e] + bias, 0.f));
      }
  }
  __syncthreads();

  // ---------- phase 5: GEMM2  (64x128) x (128x128), relu, store f32 ----------
  f32x4 acc2[4];
  #pragma unroll
  for (int m = 0; m < 4; ++m) acc2[m] = (f32x4){0.f, 0.f, 0.f, 0.f};

  #pragma unroll
  for (int kk = 0; kk < 4; ++kk) {
    const int kof = kk * 32 + lg * 8;
    const bf16x8 bfr = *(const bf16x8*)(w2t + (size_t)col * 128 + kof);
    #pragma unroll
    for (int m = 0; m < 4; ++m) {
      const bf16x8 af = *(const bf16x8*)&Hsh[m * 16 + lr][kof];
      acc2[m] = __builtin_amdgcn_mfma_f32_16x16x32_bf16(af, bfr, acc2[m], 0, 0, 0);
    }
  }
  {
    const float bias = bb2[col];
    #pragma unroll
    for (int m = 0; m < 4; ++m)
      #pragma unroll
      for (int e = 0; e < 4; ++e) {
        const int row = m * 16 + lg * 4 + e;
        out[((size_t)bb * N1_ + n0 + row) * 128 + col] = fmaxf(acc2[m][e] + bias, 0.f);
      }
  }
}

extern "C" void kernel_launch(void* const* d_in, const int* in_sizes, int n_in,
                              void* d_out, int out_size, void* d_ws, size_t ws_size,
                              hipStream_t stream) {
  const float* xyz1    = (const float*)d_in[0];
  const float* xyz2    = (const float*)d_in[1];
  const float* points1 = (const float*)d_in[2];
  const float* points2 = (const float*)d_in[3];
  const float* W1      = (const float*)d_in[4];
  const float* b1      = (const float*)d_in[5];
  const float* W2      = (const float*)d_in[6];
  const float* b2      = (const float*)d_in[7];
  float* out = (float*)d_out;

  char* ws = (char*)d_ws;
  float4*         cand  = (float4*)ws;                        // 16384*16  = 262144 B
  unsigned short* candA = (unsigned short*)(ws + 262144);     // 16384*32  = 524288 B
  unsigned short* w1t   = (unsigned short*)(ws + 786432);     // 192*128*2 =  49152 B
  unsigned short* w2t   = (unsigned short*)(ws + 835584);     // 128*128*2 =  32768 B

  prep_kernel<<<224, 256, 0, stream>>>(xyz2, W1, W2, cand, candA, w1t, w2t);
  fused_kernel<<<1024, 512, 0, stream>>>(xyz1, points1, points2, cand, candA,
                                         w1t, w2t, b1, b2, out);
}